// Round 3
// baseline (16.732 us; speedup 1.0000x reference)
//
#include <hip/hip_runtime.h>
#include <hip/hip_bf16.h>

// FWHT for 12 qubits (N=4096), batch 256, real/imag planes.
// out = FWHT(x) / 64  (H = (H2)^{⊗12}, entries ±1/64; H is never read).
//
// Radix-8: four rounds of in-register FWHT-8 over bit-groups
// [2:0], [5:3], [8:6], [11:9], with three padded-LDS exchanges.
// 512 threads/block (8 elems/thread) -> 16 waves/CU (vs 8 before).
// LDS pad: linear idx n stored at n + (n>>3)  (= (n>>3)*9 + (n&7)).
// Round A/B phases are exactly 2 lanes/bank (free); C/D <=3-way.

#define NN 4096
#define T  512

__device__ __forceinline__ void fwht8(float x[8]) {
#pragma unroll
    for (int s = 0; s < 3; ++s) {
        const int st = 1 << s;
#pragma unroll
        for (int i = 0; i < 8; ++i) {
            if ((i & st) == 0) {
                const float a = x[i];
                const float b = x[i + st];
                x[i]      = a + b;
                x[i + st] = a - b;
            }
        }
    }
}

__global__ __launch_bounds__(T)
void fwht_kernel(const float* __restrict__ xr,
                 const float* __restrict__ xi,
                 float* __restrict__ out) {
    __shared__ float s[NN + NN / 8];        // 4608 floats = 18 KiB

    const int blk = blockIdx.x;             // 0..511
    const int u   = threadIdx.x;            // 0..511

    const float* src = (blk < 256) ? (xr + (size_t)blk * NN)
                                   : (xi + (size_t)(blk - 256) * NN);
    float* dst = out + (size_t)blk * NN;

    float x[8];

    // n = w*512 + p*64 + q*8 + r   (w,p,q,r in [0,8))
    // padded LDS addr of n: (n>>3)*9 + (n&7) = w*576 + p*72 + q*9 + r

    // ---- load: 8 contiguous floats/thread (2x dwordx4); thread u = (w,p,q)
    {
        const float4* src4 = (const float4*)(src + u * 8);
        const float4 v0 = src4[0];
        const float4 v1 = src4[1];
        x[0] = v0.x; x[1] = v0.y; x[2] = v0.z; x[3] = v0.w;
        x[4] = v1.x; x[5] = v1.y; x[6] = v1.z; x[7] = v1.w;
    }

    // ---- Round A: FWHT-8 over r (bits [2:0]) ----
    fwht8(x);
#pragma unroll
    for (int r = 0; r < 8; ++r)
        s[u * 9 + r] = x[r];                // addr = (n>>3)*9 + r, n>>3 = u
    __syncthreads();

    // ---- Round B: over q (bits [5:3]); thread u = (w,p,r) ----
    {
        const int w = u >> 6, p = (u >> 3) & 7, r = u & 7;
        const int base = w * 576 + p * 72 + r;
#pragma unroll
        for (int q = 0; q < 8; ++q) x[q] = s[base + q * 9];
        fwht8(x);
#pragma unroll
        for (int q = 0; q < 8; ++q) s[base + q * 9] = x[q];  // same addrs, no bar
    }
    __syncthreads();

    // ---- Round C: over p (bits [8:6]); thread u = (w,q,r) ----
    {
        const int w = u >> 6, q = (u >> 3) & 7, r = u & 7;
        const int base = w * 576 + q * 9 + r;
#pragma unroll
        for (int p = 0; p < 8; ++p) x[p] = s[base + p * 72];
        fwht8(x);
#pragma unroll
        for (int p = 0; p < 8; ++p) s[base + p * 72] = x[p];
    }
    __syncthreads();

    // ---- Round D: over w (bits [11:9]); thread u = (p,q,r) ----
    {
        const int p = u >> 6, q = (u >> 3) & 7, r = u & 7;
        const int base = p * 72 + q * 9 + r;
#pragma unroll
        for (int w = 0; w < 8; ++w) x[w] = s[base + w * 576];
        fwht8(x);
        const float scale = 0.015625f;      // (1/sqrt(2))^12
#pragma unroll
        for (int w = 0; w < 8; ++w)
            dst[w * 512 + u] = x[w] * scale;   // 2 KiB contiguous per wave-instr
    }
}

extern "C" void kernel_launch(void* const* d_in, const int* in_sizes, int n_in,
                              void* d_out, int out_size, void* d_ws, size_t ws_size,
                              hipStream_t stream) {
    const float* xr = (const float*)d_in[0];
    const float* xi = (const float*)d_in[1];
    float* out = (float*)d_out;

    fwht_kernel<<<512, T, 0, stream>>>(xr, xi, out);
}

// Round 4
// 9.904 us; speedup vs baseline: 1.6894x; 1.6894x over previous
//
#include <hip/hip_runtime.h>
#include <hip/hip_bf16.h>

// FWHT for 12 qubits (N=4096), batch 256, real/imag planes.
// out = FWHT(x) / 64  (H = (H2)^{⊗12}, entries ±1/64; H is never read).
//
// Radix-16: three rounds of in-register FWHT-16 over bit-groups
// [3:0], [7:4], [11:8], two padded-LDS exchanges (pad: n -> n + (n>>4),
// stride-17 rows, all phases <=2 lanes/bank = free).
//
// Pipelining: each block processes BOTH vectors of one batch (real then
// imag). All 8 dwordx4 loads are issued at kernel entry; v2's memory
// latency hides under v1's compute, v1's stores drain under v2's compute.
// Grid 256 = 1 block/CU.

#define NN 4096
#define T  256

__device__ __forceinline__ void fwht16(float x[16]) {
#pragma unroll
    for (int s = 0; s < 4; ++s) {
        const int st = 1 << s;
#pragma unroll
        for (int i = 0; i < 16; ++i) {
            if ((i & st) == 0) {
                const float a = x[i];
                const float b = x[i + st];
                x[i]      = a + b;
                x[i + st] = a - b;
            }
        }
    }
}

// Three rounds + scaled store for one 4096-vector. Leaves LDS dirty;
// caller must __syncthreads() before reusing s.
__device__ __forceinline__ void fwht4096(float x[16], float* s, int t,
                                         float* __restrict__ dst) {
    // ---- Round A: bits [3:0] ----
    fwht16(x);
#pragma unroll
    for (int r = 0; r < 16; ++r)
        s[t * 17 + r] = x[r];
    __syncthreads();

    // ---- Round B: bits [7:4]; thread = (P = t>>4, R = t&15) ----
    const int baseB = (t >> 4) * 272 + (t & 15);
#pragma unroll
    for (int q = 0; q < 16; ++q) x[q] = s[baseB + q * 17];
    fwht16(x);
#pragma unroll
    for (int q = 0; q < 16; ++q) s[baseB + q * 17] = x[q];  // same addrs
    __syncthreads();

    // ---- Round C: bits [11:8]; thread = (Q = t>>4, R = t&15) ----
    const int baseC = (t >> 4) * 17 + (t & 15);
#pragma unroll
    for (int p = 0; p < 16; ++p) x[p] = s[baseC + p * 272];
    fwht16(x);

    const float scale = 0.015625f;          // (1/sqrt(2))^12
#pragma unroll
    for (int p = 0; p < 16; ++p)
        dst[p * 256 + t] = x[p] * scale;    // 1 KiB contiguous per instr
}

__global__ __launch_bounds__(T)
void fwht_kernel(const float* __restrict__ xr,
                 const float* __restrict__ xi,
                 float* __restrict__ out) {
    __shared__ float s[NN + NN / 16];       // 4352 floats = 17 KiB

    const int b = blockIdx.x;               // batch 0..255
    const int t = threadIdx.x;              // 0..255

    // Issue ALL loads for both vectors up front (8x dwordx4/thread).
    const float4* p1 = (const float4*)(xr + (size_t)b * NN + t * 16);
    const float4* p2 = (const float4*)(xi + (size_t)b * NN + t * 16);
    const float4 a0 = p1[0], a1 = p1[1], a2 = p1[2], a3 = p1[3];
    const float4 b0 = p2[0], b1 = p2[1], b2 = p2[2], b3 = p2[3];

    // ---- vector 1: real ----
    float x[16];
    x[0]  = a0.x; x[1]  = a0.y; x[2]  = a0.z; x[3]  = a0.w;
    x[4]  = a1.x; x[5]  = a1.y; x[6]  = a1.z; x[7]  = a1.w;
    x[8]  = a2.x; x[9]  = a2.y; x[10] = a2.z; x[11] = a2.w;
    x[12] = a3.x; x[13] = a3.y; x[14] = a3.z; x[15] = a3.w;
    fwht4096(x, s, t, out + (size_t)b * NN);

    __syncthreads();                        // round-C reads done before reuse

    // ---- vector 2: imag (loads arrived long ago) ----
    float y[16];
    y[0]  = b0.x; y[1]  = b0.y; y[2]  = b0.z; y[3]  = b0.w;
    y[4]  = b1.x; y[5]  = b1.y; y[6]  = b1.z; y[7]  = b1.w;
    y[8]  = b2.x; y[9]  = b2.y; y[10] = b2.z; y[11] = b2.w;
    y[12] = b3.x; y[13] = b3.y; y[14] = b3.z; y[15] = b3.w;
    fwht4096(y, s, t, out + (size_t)(256 + b) * NN);
}

extern "C" void kernel_launch(void* const* d_in, const int* in_sizes, int n_in,
                              void* d_out, int out_size, void* d_ws, size_t ws_size,
                              hipStream_t stream) {
    const float* xr = (const float*)d_in[0];
    const float* xi = (const float*)d_in[1];
    float* out = (float*)d_out;

    fwht_kernel<<<256, T, 0, stream>>>(xr, xi, out);
}